// Round 1
// baseline (938.086 us; speedup 1.0000x reference)
//
#include <hip/hip_runtime.h>
#include <hip/hip_bf16.h>

// ---------------------------------------------------------------------------
// TokenDiscrepancyLoss: loss = 0.1 * sum_{mask} [ (||t||^2 + sum_c p_c (||c||^2 - 2 t.c)) / H ]
// with p = softmax(hs @ W + b) over C=8192.
//
// Pipeline (all on `stream`):
//   memset counters -> compact active tokens -> codebook bf16+csq -> W^T bf16
//   -> fused flash-style dual-GEMM + online softmax (split over 16 C-chunks)
//   -> merge partials + exact fp32 ||t||^2 -> atomicAdd scalar loss.
// ---------------------------------------------------------------------------

#define H        1024
#define CBN      8192
#define NTOK     8192
#define NCHUNK   16
#define CW       (CBN / NCHUNK)   // 512 codewords per chunk
#define MT       64               // token rows per tile
#define NT       64               // codeword cols per inner tile
#define BK       64               // K chunk
#define LDK      (BK + 8)         // 72 elems -> 144B row stride (16B aligned)
#define NT_PER_CHUNK (CW / NT)    // 8
#define NKC      (H / BK)         // 16
#define LOSSW    0.1f

typedef __attribute__((ext_vector_type(4))) float  f32x4;
typedef __attribute__((ext_vector_type(8))) short  s16x8;   // 8 bf16 (4 VGPRs)
typedef __attribute__((ext_vector_type(8))) unsigned short u16x8;

__device__ __forceinline__ unsigned short f2bf(float f) {
  union { float f; unsigned u; } x; x.f = f;
  return (unsigned short)((x.u + 0x7FFFu + ((x.u >> 16) & 1u)) >> 16); // RNE
}
__device__ __forceinline__ u16x8 pack8(float4 a, float4 b) {
  u16x8 p;
  p[0] = f2bf(a.x); p[1] = f2bf(a.y); p[2] = f2bf(a.z); p[3] = f2bf(a.w);
  p[4] = f2bf(b.x); p[5] = f2bf(b.y); p[6] = f2bf(b.z); p[7] = f2bf(b.w);
  return p;
}
__device__ __forceinline__ f32x4 mfma16(s16x8 a, s16x8 b, f32x4 c) {
  return __builtin_amdgcn_mfma_f32_16x16x32_bf16(a, b, c, 0, 0, 0);
}

// --------------------------- compact active tokens -------------------------
// Robust to the harness presenting token_type_ids as int32 OR raw int64:
// int64 layout has all-zero hi-words at odd int32 positions; with random 0/1
// ids (~4096 ones) the int32 layout has ~2048 nonzero odd positions in the
// first 8192 ints. Decision is uniform across the grid (same data scanned).
__global__ __launch_bounds__(256) void k_compact(const int* __restrict__ ids,
                                                 int* __restrict__ list,
                                                 int* __restrict__ counter) {
  int t = threadIdx.x;
  int f = 0;
  #pragma unroll
  for (int j = 0; j < 16; ++j) f |= ids[2 * (t * 16 + j) + 1];  // idx <= 8191: safe both ways
  int anyodd = __syncthreads_or(f);

  int i = blockIdx.x * 256 + t;                 // token index 0..8191
  int v = anyodd ? ids[i] : ids[2 * i];         // int32 layout : int64 low word
  bool act = (v == 1);
  unsigned long long mask = __ballot(act);
  int lane = t & 63;
  int base = 0;
  if (lane == 0) base = atomicAdd(counter, __popcll(mask));
  base = __shfl(base, 0);
  if (act) {
    int off = __popcll(mask & ((1ull << lane) - 1ull));
    list[base + off] = i;
  }
}

// ------------------- codebook -> bf16 + per-codeword ||c||^2 ---------------
__global__ __launch_bounds__(256) void k_prep_cb(const float* __restrict__ cb,
                                                 unsigned short* __restrict__ cbb,
                                                 float* __restrict__ csq) {
  int c = blockIdx.x * 4 + (threadIdx.x >> 6);  // one wave per codeword
  int lane = threadIdx.x & 63;
  const float4* src = (const float4*)(cb + (size_t)c * H);
  float ss = 0.f;
  #pragma unroll
  for (int i = 0; i < 4; ++i) {
    float4 v = src[lane + 64 * i];
    ss += v.x * v.x + v.y * v.y + v.z * v.z + v.w * v.w;
    ushort4 p;
    p.x = f2bf(v.x); p.y = f2bf(v.y); p.z = f2bf(v.z); p.w = f2bf(v.w);
    *(ushort4*)(cbb + (size_t)c * H + (size_t)(lane + 64 * i) * 4) = p;
  }
  #pragma unroll
  for (int d = 1; d < 64; d <<= 1) ss += __shfl_xor(ss, d);
  if (lane == 0) csq[c] = ss;
}

// --------------------- W [H,C] fp32 -> W^T [C,H] bf16 ----------------------
__global__ __launch_bounds__(256) void k_prep_w(const float* __restrict__ W,
                                                unsigned short* __restrict__ Wtb) {
  __shared__ float tile[64][68];                // +4 pad breaks bank conflicts
  int c0 = blockIdx.x * 64, k0 = blockIdx.y * 64;
  int r = threadIdx.x >> 2, q = threadIdx.x & 3;
  const float4* src = (const float4*)(W + (size_t)(k0 + r) * CBN + c0);
  #pragma unroll
  for (int i = 0; i < 4; ++i) {
    float4 v = src[q * 4 + i];
    *(float4*)&tile[r][q * 16 + i * 4] = v;
  }
  __syncthreads();
  unsigned short* dst = Wtb + (size_t)(c0 + r) * H + k0;
  #pragma unroll
  for (int i = 0; i < 4; ++i) {
    ushort4 p;
    p.x = f2bf(tile[q * 16 + i * 4 + 0][r]);
    p.y = f2bf(tile[q * 16 + i * 4 + 1][r]);
    p.z = f2bf(tile[q * 16 + i * 4 + 2][r]);
    p.w = f2bf(tile[q * 16 + i * 4 + 3][r]);
    *(ushort4*)(dst + q * 16 + i * 4) = p;
  }
}

// ------------------ fused dual-GEMM + online softmax -----------------------
// grid (NTOK/MT, NCHUNK), block 256 (4 waves). Wave w owns rows w*16..w*16+15
// of the 64-token tile, all 64 cols of each N-tile. C/D frag: row=quad*4+reg,
// col=lane&15 -> row-wise softmax reduction is a quad-local shfl_xor.
__global__ __launch_bounds__(256) void k_fused(
    const float* __restrict__ hs, const float* __restrict__ tg,
    const unsigned short* __restrict__ Wtb, const unsigned short* __restrict__ Cbb,
    const float* __restrict__ bias, const float* __restrict__ csq,
    const int* __restrict__ list, const int* __restrict__ counter,
    float* __restrict__ pm, float* __restrict__ pl, float* __restrict__ ps) {
  const int n = *counter;
  const int tile = blockIdx.x;
  if (tile * MT >= n) return;
  const int chunk = blockIdx.y;

  __shared__ __align__(16) unsigned short sA1[MT][LDK];  // hs tile (bf16)
  __shared__ __align__(16) unsigned short sA2[MT][LDK];  // target tile
  __shared__ __align__(16) unsigned short sB1[NT][LDK];  // W^T rows
  __shared__ __align__(16) unsigned short sB2[NT][LDK];  // codebook rows
  __shared__ int stok[MT];

  const int tid = threadIdx.x;
  if (tid < MT) {
    int ga = tile * MT + tid;
    stok[tid] = list[(ga < n) ? ga : 0];       // pad rows read token0; ignored at merge
  }
  __syncthreads();

  const int w = tid >> 6, lane = tid & 63;
  const int quad = lane >> 4, lcol = lane & 15;
  const int r = tid >> 2, q = tid & 3;         // staging: 4 threads x 16 cols per row

  const float* arow1 = hs + (size_t)stok[r] * H + q * 16;
  const float* arow2 = tg + (size_t)stok[r] * H + q * 16;

  float m_[4] = {-1e30f, -1e30f, -1e30f, -1e30f};
  float l_[4] = {0.f, 0.f, 0.f, 0.f};
  float s_[4] = {0.f, 0.f, 0.f, 0.f};

  const int c0 = chunk * CW;

  for (int nt = 0; nt < NT_PER_CHUNK; ++nt) {
    const int nb0 = c0 + nt * NT;
    f32x4 acc1[4], acc2[4];
    #pragma unroll
    for (int i = 0; i < 4; ++i) {
      acc1[i] = (f32x4){0.f, 0.f, 0.f, 0.f};
      acc2[i] = (f32x4){0.f, 0.f, 0.f, 0.f};
    }
    const unsigned short* brow1 = Wtb + (size_t)(nb0 + r) * H + q * 16;
    const unsigned short* brow2 = Cbb + (size_t)(nb0 + r) * H + q * 16;

    for (int kc = 0; kc < NKC; ++kc) {
      __syncthreads();
      {  // stage A: fp32 -> bf16, 16 elems/thread/array
        const float* a1 = arow1 + kc * BK;
        const float* a2 = arow2 + kc * BK;
        #pragma unroll
        for (int i = 0; i < 2; ++i) {
          float4 v0 = *(const float4*)(a1 + i * 8);
          float4 v1 = *(const float4*)(a1 + i * 8 + 4);
          *(u16x8*)&sA1[r][q * 16 + i * 8] = pack8(v0, v1);
          v0 = *(const float4*)(a2 + i * 8);
          v1 = *(const float4*)(a2 + i * 8 + 4);
          *(u16x8*)&sA2[r][q * 16 + i * 8] = pack8(v0, v1);
        }
      }
      {  // stage B: bf16 pass-through
        const unsigned short* b1 = brow1 + kc * BK;
        const unsigned short* b2 = brow2 + kc * BK;
        #pragma unroll
        for (int i = 0; i < 2; ++i) {
          *(u16x8*)&sB1[r][q * 16 + i * 8] = *(const u16x8*)(b1 + i * 8);
          *(u16x8*)&sB2[r][q * 16 + i * 8] = *(const u16x8*)(b2 + i * 8);
        }
      }
      __syncthreads();
      #pragma unroll
      for (int ks = 0; ks < BK / 32; ++ks) {
        const int ko = ks * 32 + quad * 8;
        s16x8 a1 = *(const s16x8*)&sA1[w * 16 + lcol][ko];
        s16x8 a2 = *(const s16x8*)&sA2[w * 16 + lcol][ko];
        #pragma unroll
        for (int nb = 0; nb < 4; ++nb) {
          s16x8 b1 = *(const s16x8*)&sB1[nb * 16 + lcol][ko];
          s16x8 b2 = *(const s16x8*)&sB2[nb * 16 + lcol][ko];
          acc1[nb] = mfma16(a1, b1, acc1[nb]);
          acc2[nb] = mfma16(a2, b2, acc2[nb]);
        }
      }
    }

    // online softmax update over this 64-col tile
    float lg[4][4], ct[4][4];
    #pragma unroll
    for (int nb = 0; nb < 4; ++nb) {
      const int col = nb0 + nb * 16 + lcol;
      const float bv = bias[col];
      const float cq = csq[col];
      #pragma unroll
      for (int j = 0; j < 4; ++j) {
        lg[nb][j] = acc1[nb][j] + bv;          // logit
        ct[nb][j] = cq - 2.f * acc2[nb][j];    // ||c||^2 - 2 t.c
      }
    }
    #pragma unroll
    for (int j = 0; j < 4; ++j) {
      float tmax = fmaxf(fmaxf(lg[0][j], lg[1][j]), fmaxf(lg[2][j], lg[3][j]));
      #pragma unroll
      for (int d = 1; d < 16; d <<= 1) tmax = fmaxf(tmax, __shfl_xor(tmax, d));
      const float nm = fmaxf(m_[j], tmax);
      const float sc = __expf(m_[j] - nm);     // exp(-1e30-..)=0 on first tile
      float le = 0.f, se = 0.f;
      #pragma unroll
      for (int nb = 0; nb < 4; ++nb) {
        const float e = __expf(lg[nb][j] - nm);
        le += e; se += e * ct[nb][j];
      }
      l_[j] = l_[j] * sc + le;
      s_[j] = s_[j] * sc + se;
      m_[j] = nm;
    }
  }

  // fold per-lane column partials across the 16 lanes of each quad
  #pragma unroll
  for (int j = 0; j < 4; ++j) {
    #pragma unroll
    for (int d = 1; d < 16; d <<= 1) {
      l_[j] += __shfl_xor(l_[j], d);
      s_[j] += __shfl_xor(s_[j], d);
    }
  }
  if (lcol == 0) {
    #pragma unroll
    for (int j = 0; j < 4; ++j) {
      const int ga = tile * MT + w * 16 + quad * 4 + j;
      pm[chunk * NTOK + ga] = m_[j];
      pl[chunk * NTOK + ga] = l_[j];
      ps[chunk * NTOK + ga] = s_[j];
    }
  }
}

// ----------------- merge chunk partials + exact ||t||^2 --------------------
__global__ __launch_bounds__(256) void k_merge(
    const float* __restrict__ tg, const int* __restrict__ list,
    const int* __restrict__ counter,
    const float* __restrict__ pm, const float* __restrict__ pl,
    const float* __restrict__ ps, float* __restrict__ out) {
  const int n = *counter;
  const int ga = blockIdx.x * 4 + (threadIdx.x >> 6);  // one wave per token
  if (ga >= n) return;
  const int lane = threadIdx.x & 63;
  const int idx = list[ga];
  const float4* tp = (const float4*)(tg + (size_t)idx * H);
  float ts = 0.f;
  #pragma unroll
  for (int i = 0; i < 4; ++i) {
    float4 v = tp[lane + 64 * i];
    ts += v.x * v.x + v.y * v.y + v.z * v.z + v.w * v.w;
  }
  #pragma unroll
  for (int d = 1; d < 64; d <<= 1) ts += __shfl_xor(ts, d);
  if (lane == 0) {
    float M = -1e30f;
    #pragma unroll
    for (int j = 0; j < NCHUNK; ++j) M = fmaxf(M, pm[j * NTOK + ga]);
    float L = 0.f, S = 0.f;
    #pragma unroll
    for (int j = 0; j < NCHUNK; ++j) {
      const float e = __expf(pm[j * NTOK + ga] - M);
      L += pl[j * NTOK + ga] * e;
      S += ps[j * NTOK + ga] * e;
    }
    const float val = (ts + S / L) * (LOSSW / (float)H);
    atomicAdd(out, val);
  }
}

// ---------------------------------------------------------------------------
extern "C" void kernel_launch(void* const* d_in, const int* in_sizes, int n_in,
                              void* d_out, int out_size, void* d_ws, size_t ws_size,
                              hipStream_t stream) {
  const float* hs   = (const float*)d_in[0];   // [8192,1024]
  const int*   ids  = (const int*)d_in[1];     // token_type_ids (layout auto-detected)
  const float* tg   = (const float*)d_in[2];   // [8192,1024]
  const float* cb   = (const float*)d_in[3];   // [8192,1024]
  const float* W    = (const float*)d_in[4];   // [1024,8192]
  const float* bias = (const float*)d_in[5];   // [8192]

  char* ws = (char*)d_ws;
  // ws layout
  constexpr size_t OFF_CNT  = 0;
  constexpr size_t OFF_WTB  = 256;                                  // bf16 [C][H] 16 MiB
  constexpr size_t OFF_CBB  = OFF_WTB + (size_t)CBN * H * 2;        // bf16 [C][H] 16 MiB
  constexpr size_t OFF_CSQ  = OFF_CBB + (size_t)CBN * H * 2;        // f32 [C]
  constexpr size_t OFF_LIST = OFF_CSQ + (size_t)CBN * 4;            // i32 [NTOK]
  constexpr size_t OFF_PM   = OFF_LIST + (size_t)NTOK * 4;          // f32 [NCHUNK][NTOK]
  constexpr size_t OFF_PL   = OFF_PM + (size_t)NCHUNK * NTOK * 4;
  constexpr size_t OFF_PS   = OFF_PL + (size_t)NCHUNK * NTOK * 4;

  int*            counter = (int*)(ws + OFF_CNT);
  unsigned short* Wtb     = (unsigned short*)(ws + OFF_WTB);
  unsigned short* Cbb     = (unsigned short*)(ws + OFF_CBB);
  float*          csq     = (float*)(ws + OFF_CSQ);
  int*            list    = (int*)(ws + OFF_LIST);
  float*          pm      = (float*)(ws + OFF_PM);
  float*          pl      = (float*)(ws + OFF_PL);
  float*          ps      = (float*)(ws + OFF_PS);

  hipMemsetAsync(counter, 0, sizeof(int), stream);
  hipMemsetAsync(d_out, 0, sizeof(float), stream);

  k_compact<<<NTOK / 256, 256, 0, stream>>>(ids, list, counter);
  k_prep_cb<<<CBN / 4, 256, 0, stream>>>(cb, Cbb, csq);
  k_prep_w<<<dim3(CBN / 64, H / 64), 256, 0, stream>>>(W, Wtb);
  k_fused<<<dim3(NTOK / MT, NCHUNK), 256, 0, stream>>>(
      hs, tg, Wtb, Cbb, bias, csq, list, counter, pm, pl, ps);
  k_merge<<<NTOK / 4, 256, 0, stream>>>(tg, list, counter, pm, pl, ps, (float*)d_out);
}

// Round 2
// 462.568 us; speedup vs baseline: 2.0280x; 2.0280x over previous
//
#include <hip/hip_runtime.h>
#include <hip/hip_bf16.h>

// ---------------------------------------------------------------------------
// TokenDiscrepancyLoss: loss = 0.1 * sum_{mask} [ (||t||^2 + sum_c p_c (||c||^2 - 2 t.c)) / H ]
// with p = softmax(hs @ W + b) over C=8192.
//
// R2 structure: compact -> prep (bf16 W^T, bf16 codebook+csq, gathered bf16
// hs/tg + exact ||t||^2) -> fused 128x128-tile dual-GEMM with global_load_lds
// (xor-swizzled) + one softmax partial per 64-col wave strip -> merge.
// ---------------------------------------------------------------------------

#define H        1024
#define CBN      8192
#define NTOK     8192
#define MT       128              // token rows per tile
#define NTILE    128              // codeword cols per tile
#define BK       64               // K chunk
#define NKC      (H / BK)         // 16
#define NCHK     (CBN / 64)       // 128 partial strips (one per 64-col wave tile)
#define LOSSW    0.1f

typedef __attribute__((ext_vector_type(4))) float  f32x4;
typedef __attribute__((ext_vector_type(8))) short  s16x8;   // 8 bf16 (4 VGPRs)

__device__ __forceinline__ unsigned short f2bf(float f) {
  union { float f; unsigned u; } x; x.f = f;
  return (unsigned short)((x.u + 0x7FFFu + ((x.u >> 16) & 1u)) >> 16); // RNE
}
__device__ __forceinline__ f32x4 mfma16(s16x8 a, s16x8 b, f32x4 c) {
  return __builtin_amdgcn_mfma_f32_16x16x32_bf16(a, b, c, 0, 0, 0);
}
// async global->LDS DMA, 16B/lane; LDS dest = wave-uniform base + lane*16
__device__ __forceinline__ void load_lds16(const void* g, void* l) {
  __builtin_amdgcn_global_load_lds((const __attribute__((address_space(1))) void*)g,
                                   (__attribute__((address_space(3))) void*)l,
                                   16, 0, 0);
}

// --------------------------- compact active tokens -------------------------
// Robust to token_type_ids presented as int32 OR raw int64 (hi-words zero).
__global__ __launch_bounds__(256) void k_compact(const int* __restrict__ ids,
                                                 int* __restrict__ list,
                                                 int* __restrict__ counter) {
  int t = threadIdx.x;
  int f = 0;
  #pragma unroll
  for (int j = 0; j < 16; ++j) f |= ids[2 * (t * 16 + j) + 1];
  int anyodd = __syncthreads_or(f);

  int i = blockIdx.x * 256 + t;
  int v = anyodd ? ids[i] : ids[2 * i];
  bool act = (v == 1);
  unsigned long long mask = __ballot(act);
  int lane = t & 63;
  int base = 0;
  if (lane == 0) base = atomicAdd(counter, __popcll(mask));
  base = __shfl(base, 0);
  if (act) {
    int off = __popcll(mask & ((1ull << lane) - 1ull));
    list[base + off] = i;
  }
}

// ------------------- codebook -> bf16 + per-codeword ||c||^2 ---------------
__global__ __launch_bounds__(256) void k_prep_cb(const float* __restrict__ cb,
                                                 unsigned short* __restrict__ cbb,
                                                 float* __restrict__ csq) {
  int c = blockIdx.x * 4 + (threadIdx.x >> 6);
  int lane = threadIdx.x & 63;
  const float4* src = (const float4*)(cb + (size_t)c * H);
  float ss = 0.f;
  #pragma unroll
  for (int i = 0; i < 4; ++i) {
    float4 v = src[lane + 64 * i];
    ss += v.x * v.x + v.y * v.y + v.z * v.z + v.w * v.w;
    ushort4 p;
    p.x = f2bf(v.x); p.y = f2bf(v.y); p.z = f2bf(v.z); p.w = f2bf(v.w);
    *(ushort4*)(cbb + (size_t)c * H + (size_t)(lane + 64 * i) * 4) = p;
  }
  #pragma unroll
  for (int d = 1; d < 64; d <<= 1) ss += __shfl_xor(ss, d);
  if (lane == 0) csq[c] = ss;
}

// --------------------- W [H,C] fp32 -> W^T [C,H] bf16 ----------------------
__global__ __launch_bounds__(256) void k_prep_w(const float* __restrict__ W,
                                                unsigned short* __restrict__ Wtb) {
  __shared__ float tile[64][68];
  int c0 = blockIdx.x * 64, k0 = blockIdx.y * 64;
  int r = threadIdx.x >> 2, q = threadIdx.x & 3;
  const float4* src = (const float4*)(W + (size_t)(k0 + r) * CBN + c0);
  #pragma unroll
  for (int i = 0; i < 4; ++i) {
    float4 v = src[q * 4 + i];
    *(float4*)&tile[r][q * 16 + i * 4] = v;
  }
  __syncthreads();
  unsigned short* dst = Wtb + (size_t)(c0 + r) * H + k0;
  #pragma unroll
  for (int i = 0; i < 4; ++i) {
    ushort4 p;
    p.x = f2bf(tile[q * 16 + i * 4 + 0][r]);
    p.y = f2bf(tile[q * 16 + i * 4 + 1][r]);
    p.z = f2bf(tile[q * 16 + i * 4 + 2][r]);
    p.w = f2bf(tile[q * 16 + i * 4 + 3][r]);
    *(ushort4*)(dst + q * 16 + i * 4) = p;
  }
}

// --------- gather active tokens -> bf16 rows + exact fp32 ||t||^2 ----------
__global__ __launch_bounds__(256) void k_prep_a(
    const float* __restrict__ hs, const float* __restrict__ tg,
    const int* __restrict__ list, const int* __restrict__ counter,
    unsigned short* __restrict__ Ahs, unsigned short* __restrict__ Atg,
    float* __restrict__ tsq) {
  const int n = *counter;
  const int n_pad = (n + MT - 1) & ~(MT - 1);
  const int ga = blockIdx.x * 4 + (threadIdx.x >> 6);
  if (ga >= n_pad) return;
  const int lane = threadIdx.x & 63;
  const int tok = list[(ga < n) ? ga : 0];   // pad rows duplicate token 0
  const float4* h4 = (const float4*)(hs + (size_t)tok * H);
  const float4* t4 = (const float4*)(tg + (size_t)tok * H);
  unsigned short* ah = Ahs + (size_t)ga * H;
  unsigned short* at = Atg + (size_t)ga * H;
  float ss = 0.f;
  #pragma unroll
  for (int i = 0; i < 4; ++i) {
    float4 v = h4[lane + 64 * i];
    ushort4 p;
    p.x = f2bf(v.x); p.y = f2bf(v.y); p.z = f2bf(v.z); p.w = f2bf(v.w);
    *(ushort4*)(ah + (size_t)(lane + 64 * i) * 4) = p;
    float4 u = t4[lane + 64 * i];
    ss += u.x * u.x + u.y * u.y + u.z * u.z + u.w * u.w;
    ushort4 q;
    q.x = f2bf(u.x); q.y = f2bf(u.y); q.z = f2bf(u.z); q.w = f2bf(u.w);
    *(ushort4*)(at + (size_t)(lane + 64 * i) * 4) = q;
  }
  #pragma unroll
  for (int d = 1; d < 64; d <<= 1) ss += __shfl_xor(ss, d);
  if (lane == 0) tsq[ga] = ss;
}

// ------------------ fused dual-GEMM + softmax partials ---------------------
// grid (NTOK/MT, CBN/NTILE) = (64, 64); block 256 = 4 waves in 2x2.
// Wave (wr,wc) computes rows wr*64..+63 x cols wc*64..+63 for BOTH gemms,
// accumulating over full K=1024, then emits one (m,l,s) softmax partial per
// row for its 64-col strip (chunk id = blockIdx.y*2 + wc).
// LDS: unpadded [128][64] bf16 per array, filled by global_load_lds with the
// source-side xor swizzle chunk' = chunk ^ (row&7) -> conflict-free frag reads.
__global__ __launch_bounds__(256, 2) void k_fused(
    const unsigned short* __restrict__ Ahs, const unsigned short* __restrict__ Atg,
    const unsigned short* __restrict__ Wtb, const unsigned short* __restrict__ Cbb,
    const float* __restrict__ bias, const float* __restrict__ csq,
    const int* __restrict__ counter,
    float* __restrict__ pm, float* __restrict__ pl, float* __restrict__ ps) {
  const int n = *counter;
  const int tilex = blockIdx.x;
  if (tilex * MT >= n) return;
  const int tiley = blockIdx.y;

  __shared__ __align__(16) unsigned short sA1[MT * BK];
  __shared__ __align__(16) unsigned short sA2[MT * BK];
  __shared__ __align__(16) unsigned short sB1[NTILE * BK];
  __shared__ __align__(16) unsigned short sB2[NTILE * BK];

  const int tid  = threadIdx.x;
  const int w    = tid >> 6, lane = tid & 63;
  const int wr   = w >> 1,   wc   = w & 1;
  const int quad = lane >> 4, lcol = lane & 15;
  const int swz  = lcol & 7;

  // DMA source addressing: lane covers row (li*8 + lane/8), lds-chunk lane&7,
  // which must hold global chunk (lane&7) ^ ((lane>>3)&7).
  const int rsub = lane >> 3;
  const int cg   = (lane & 7) ^ rsub;
  const size_t rowA0H = (size_t)tilex * MT * H;
  const size_t colB0H = (size_t)tiley * NTILE * H;

  f32x4 acc1[4][4], acc2[4][4];
  #pragma unroll
  for (int mb = 0; mb < 4; ++mb)
    #pragma unroll
    for (int nb = 0; nb < 4; ++nb) {
      acc1[mb][nb] = (f32x4){0.f, 0.f, 0.f, 0.f};
      acc2[mb][nb] = (f32x4){0.f, 0.f, 0.f, 0.f};
    }

  for (int kc = 0; kc < NKC; ++kc) {
    // ---- stage: 16 DMA wave-loads per wave (4 per array) ----
    #pragma unroll
    for (int i = 0; i < 4; ++i) {
      const int li  = w + 4 * i;              // wave-load index 0..15
      const int rit = li * 8 + rsub;          // row in tile 0..127
      const size_t goff = (size_t)rit * H + (size_t)(kc * BK + cg * 8);
      load_lds16(Ahs + rowA0H + goff, &sA1[li * 512]);
      load_lds16(Atg + rowA0H + goff, &sA2[li * 512]);
      load_lds16(Wtb + colB0H + goff, &sB1[li * 512]);
      load_lds16(Cbb + colB0H + goff, &sB2[li * 512]);
    }
    __syncthreads();   // drains vmcnt(0): DMA complete

    // ---- compute: 2 ks x 2 gemms x 16 MFMA ----
    #pragma unroll
    for (int ks = 0; ks < 2; ++ks) {
      const int cA = (((ks * 4 + quad) ^ swz) * 8);   // swizzled elem offset
      {
        s16x8 af[4], bf[4];
        #pragma unroll
        for (int mb = 0; mb < 4; ++mb)
          af[mb] = *(const s16x8*)&sA1[(wr * 64 + mb * 16 + lcol) * BK + cA];
        #pragma unroll
        for (int nb = 0; nb < 4; ++nb)
          bf[nb] = *(const s16x8*)&sB1[(wc * 64 + nb * 16 + lcol) * BK + cA];
        #pragma unroll
        for (int mb = 0; mb < 4; ++mb)
          #pragma unroll
          for (int nb = 0; nb < 4; ++nb)
            acc1[mb][nb] = mfma16(af[mb], bf[nb], acc1[mb][nb]);
      }
      {
        s16x8 af[4], bf[4];
        #pragma unroll
        for (int mb = 0; mb < 4; ++mb)
          af[mb] = *(const s16x8*)&sA2[(wr * 64 + mb * 16 + lcol) * BK + cA];
        #pragma unroll
        for (int nb = 0; nb < 4; ++nb)
          bf[nb] = *(const s16x8*)&sB2[(wc * 64 + nb * 16 + lcol) * BK + cA];
        #pragma unroll
        for (int mb = 0; mb < 4; ++mb)
          #pragma unroll
          for (int nb = 0; nb < 4; ++nb)
            acc2[mb][nb] = mfma16(af[mb], bf[nb], acc2[mb][nb]);
      }
    }
    __syncthreads();   // protect LDS from next iter's DMA
  }

  // ---- epilogue: softmax partial over this wave's 64-col strip ----
  float bv[4], cq[4];
  #pragma unroll
  for (int nb = 0; nb < 4; ++nb) {
    const int col = tiley * NTILE + wc * 64 + nb * 16 + lcol;
    bv[nb] = bias[col];
    cq[nb] = csq[col];
  }
  const int chunk = tiley * 2 + wc;
  #pragma unroll
  for (int mb = 0; mb < 4; ++mb) {
    #pragma unroll
    for (int j = 0; j < 4; ++j) {
      float lg[4], ct[4];
      #pragma unroll
      for (int nb = 0; nb < 4; ++nb) {
        lg[nb] = acc1[mb][nb][j] + bv[nb];
        ct[nb] = cq[nb] - 2.f * acc2[mb][nb][j];
      }
      float tmax = fmaxf(fmaxf(lg[0], lg[1]), fmaxf(lg[2], lg[3]));
      #pragma unroll
      for (int d = 1; d < 16; d <<= 1) tmax = fmaxf(tmax, __shfl_xor(tmax, d));
      float le = 0.f, se = 0.f;
      #pragma unroll
      for (int nb = 0; nb < 4; ++nb) {
        const float e = __expf(lg[nb] - tmax);
        le += e; se += e * ct[nb];
      }
      #pragma unroll
      for (int d = 1; d < 16; d <<= 1) {
        le += __shfl_xor(le, d);
        se += __shfl_xor(se, d);
      }
      if (lcol == 0) {
        const int row = tilex * MT + wr * 64 + mb * 16 + quad * 4 + j;
        pm[chunk * NTOK + row] = tmax;
        pl[chunk * NTOK + row] = le;
        ps[chunk * NTOK + row] = se;
      }
    }
  }
}

// ----------------- merge strip partials -> scalar loss ---------------------
__global__ __launch_bounds__(256) void k_merge(
    const int* __restrict__ counter, const float* __restrict__ tsq,
    const float* __restrict__ pm, const float* __restrict__ pl,
    const float* __restrict__ ps, float* __restrict__ out) {
  const int n = *counter;
  const int ga = blockIdx.x * 256 + threadIdx.x;
  float val = 0.f;
  if (ga < n) {
    float M = -1e30f;
    for (int j = 0; j < NCHK; ++j) M = fmaxf(M, pm[j * NTOK + ga]);
    float L = 0.f, S = 0.f;
    for (int j = 0; j < NCHK; ++j) {
      const float e = __expf(pm[j * NTOK + ga] - M);
      L += pl[j * NTOK + ga] * e;
      S += ps[j * NTOK + ga] * e;
    }
    val = (tsq[ga] + S / L) * (LOSSW / (float)H);
  }
  #pragma unroll
  for (int d = 1; d < 64; d <<= 1) val += __shfl_xor(val, d);
  __shared__ float wsum[4];
  if ((threadIdx.x & 63) == 0) wsum[threadIdx.x >> 6] = val;
  __syncthreads();
  if (threadIdx.x == 0)
    atomicAdd(out, wsum[0] + wsum[1] + wsum[2] + wsum[3]);
}

// ---------------------------------------------------------------------------
extern "C" void kernel_launch(void* const* d_in, const int* in_sizes, int n_in,
                              void* d_out, int out_size, void* d_ws, size_t ws_size,
                              hipStream_t stream) {
  const float* hs   = (const float*)d_in[0];
  const int*   ids  = (const int*)d_in[1];
  const float* tg   = (const float*)d_in[2];
  const float* cb   = (const float*)d_in[3];
  const float* W    = (const float*)d_in[4];
  const float* bias = (const float*)d_in[5];

  char* ws = (char*)d_ws;
  constexpr size_t OFF_CNT  = 0;
  constexpr size_t OFF_WTB  = 256;
  constexpr size_t OFF_CBB  = OFF_WTB  + (size_t)CBN * H * 2;    // +16 MiB
  constexpr size_t OFF_AHS  = OFF_CBB  + (size_t)CBN * H * 2;    // +16 MiB
  constexpr size_t OFF_ATG  = OFF_AHS  + (size_t)NTOK * H * 2;   // +16 MiB
  constexpr size_t OFF_CSQ  = OFF_ATG  + (size_t)NTOK * H * 2;   // +16 MiB
  constexpr size_t OFF_TSQ  = OFF_CSQ  + (size_t)CBN * 4;
  constexpr size_t OFF_LIST = OFF_TSQ  + (size_t)NTOK * 4;
  constexpr size_t OFF_PM   = OFF_LIST + (size_t)NTOK * 4;
  constexpr size_t OFF_PL   = OFF_PM   + (size_t)NCHK * NTOK * 4;
  constexpr size_t OFF_PS   = OFF_PL   + (size_t)NCHK * NTOK * 4;

  int*            counter = (int*)(ws + OFF_CNT);
  unsigned short* Wtb     = (unsigned short*)(ws + OFF_WTB);
  unsigned short* Cbb     = (unsigned short*)(ws + OFF_CBB);
  unsigned short* Ahs     = (unsigned short*)(ws + OFF_AHS);
  unsigned short* Atg     = (unsigned short*)(ws + OFF_ATG);
  float*          csq     = (float*)(ws + OFF_CSQ);
  float*          tsq     = (float*)(ws + OFF_TSQ);
  int*            list    = (int*)(ws + OFF_LIST);
  float*          pm      = (float*)(ws + OFF_PM);
  float*          pl      = (float*)(ws + OFF_PL);
  float*          ps      = (float*)(ws + OFF_PS);

  hipMemsetAsync(counter, 0, sizeof(int), stream);
  hipMemsetAsync(d_out, 0, sizeof(float), stream);

  k_compact<<<NTOK / 256, 256, 0, stream>>>(ids, list, counter);
  k_prep_cb<<<CBN / 4, 256, 0, stream>>>(cb, Cbb, csq);
  k_prep_w<<<dim3(CBN / 64, H / 64), 256, 0, stream>>>(W, Wtb);
  k_prep_a<<<NTOK / 4, 256, 0, stream>>>(hs, tg, list, counter, Ahs, Atg, tsq);
  k_fused<<<dim3(NTOK / MT, CBN / NTILE), 256, 0, stream>>>(
      Ahs, Atg, Wtb, Cbb, bias, csq, counter, pm, pl, ps);
  k_merge<<<NTOK / 256, 256, 0, stream>>>(counter, tsq, pm, pl, ps, (float*)d_out);
}